// Round 1
// baseline (224.473 us; speedup 1.0000x reference)
//
#include <hip/hip_runtime.h>

#define NB   131072   // batch rows
#define TPB  256      // threads per block = rows per block
#define FANIN 260

__device__ __forceinline__ float sigm_(float x) { return 1.0f / (1.0f + __expf(-x)); }
__device__ __forceinline__ float tanh_(float x) { return 1.0f - 2.0f / (__expf(2.0f * x) + 1.0f); }

// Repack the four [4,260] weight matrices into k-major Wp[k][16] (gw = g*4+w)
// and fuse bias+theta into bth[16]. Runs every launch (ws is re-poisoned).
__global__ void qlstm_prep(const float* __restrict__ Wf, const float* __restrict__ bf,
                           const float* __restrict__ Wi, const float* __restrict__ bi,
                           const float* __restrict__ Wu, const float* __restrict__ bu,
                           const float* __restrict__ Wo, const float* __restrict__ bo,
                           const float* __restrict__ thf, const float* __restrict__ thi,
                           const float* __restrict__ thu, const float* __restrict__ tho,
                           float* __restrict__ Wp, float* __restrict__ bth) {
    int t = blockIdx.x * blockDim.x + threadIdx.x;
    if (t < FANIN * 16) {
        int k = t >> 4, gw = t & 15, g = gw >> 2, w = gw & 3;
        const float* Wg = (g == 0) ? Wf : (g == 1) ? Wi : (g == 2) ? Wu : Wo;
        Wp[t] = Wg[w * FANIN + k];
    }
    if (t < 16) {
        int g = t >> 2, w = t & 3;
        const float* bg = (g == 0) ? bf  : (g == 1) ? bi  : (g == 2) ? bu  : bo;
        const float* tg = (g == 0) ? thf : (g == 1) ? thi : (g == 2) ? thu : tho;
        bth[t] = bg[w] + tg[w];
    }
}

__global__ __launch_bounds__(TPB) void qlstm_main(
        const float* __restrict__ x, const float* __restrict__ hx,
        const float* __restrict__ cx, const float* __restrict__ Wp,
        const float* __restrict__ bth, float* __restrict__ out) {
    // LDS tile: 256 rows x 32 cols, +1 pad -> bank (tid+kk)%32, conflict-free.
    __shared__ float xs[TPB * 33];

    const int tid  = threadIdx.x;
    const int row0 = blockIdx.x * TPB;
    const int row  = row0 + tid;

    float acc[16];
#pragma unroll
    for (int j = 0; j < 16; ++j) acc[j] = 0.0f;

    const float4* x4 = (const float4*)x;  // x is [NB][256] = [NB][64 float4]

    for (int stage = 0; stage < 8; ++stage) {
        // Stage 32 columns of 256 rows into LDS. 8 float4 per thread.
        // f = tid + 256*u -> r = f>>3, c4 = f&7; 8 consecutive lanes read
        // one row's 128 B segment -> full-line coalescing.
#pragma unroll
        for (int u = 0; u < 8; ++u) {
            int f  = tid + (u << 8);
            int r  = f >> 3;
            int c4 = f & 7;
            float4 v = x4[(size_t)(row0 + r) * 64 + stage * 8 + c4];
            float* dst = &xs[r * 33 + (c4 << 2)];
            dst[0] = v.x; dst[1] = v.y; dst[2] = v.z; dst[3] = v.w;
        }
        __syncthreads();

        const float* xrow = &xs[tid * 33];
        const float* wbase = Wp + stage * 32 * 16;
#pragma unroll
        for (int kk = 0; kk < 32; ++kk) {
            float xv = xrow[kk];
            const float* wp = wbase + kk * 16;  // wave-uniform -> s_load
#pragma unroll
            for (int j = 0; j < 16; ++j) acc[j] = fmaf(xv, wp[j], acc[j]);
        }
        __syncthreads();
    }

    // Tail: k = 256..259 come from hx[row][0..3] (coalesced float4).
    float4 hv = ((const float4*)hx)[row];
    {
        const float* wp = Wp + 256 * 16;
#pragma unroll
        for (int j = 0; j < 16; ++j) acc[j] = fmaf(hv.x, wp[j],      acc[j]);
#pragma unroll
        for (int j = 0; j < 16; ++j) acc[j] = fmaf(hv.y, wp[16 + j], acc[j]);
#pragma unroll
        for (int j = 0; j < 16; ++j) acc[j] = fmaf(hv.z, wp[32 + j], acc[j]);
#pragma unroll
        for (int j = 0; j < 16; ++j) acc[j] = fmaf(hv.w, wp[48 + j], acc[j]);
    }

    // Quantum gate closed form: c_w = cos(angle_w + b_w + th_w);
    // E0 = c1*c2*c3, E1 = c0*c1, E2 = c0*c1*c2, E3 = c0*c1*c2*c3.
    float co[16];
#pragma unroll
    for (int j = 0; j < 16; ++j) co[j] = __cosf(acc[j] + bth[j]);

    float G[16];
#pragma unroll
    for (int g = 0; g < 4; ++g) {
        float c0 = co[g * 4 + 0], c1 = co[g * 4 + 1];
        float c2 = co[g * 4 + 2], c3 = co[g * 4 + 3];
        float e1 = c0 * c1;
        float e2 = e1 * c2;
        float e3 = e2 * c3;
        float e0 = c1 * c2 * c3;
        G[g * 4 + 0] = e0; G[g * 4 + 1] = e1; G[g * 4 + 2] = e2; G[g * 4 + 3] = e3;
    }

    float4 cxv = ((const float4*)cx)[row];
    float cxa[4] = {cxv.x, cxv.y, cxv.z, cxv.w};

    float hn[4], cn[4];
#pragma unroll
    for (int w = 0; w < 4; ++w) {
        float fg = sigm_(G[0 * 4 + w]);
        float ig = sigm_(G[1 * 4 + w]);
        float ug = tanh_(G[2 * 4 + w]);
        float og = sigm_(G[3 * 4 + w]);
        float c_ = fg * cxa[w] + ig * ug;
        cn[w] = c_;
        hn[w] = og * tanh_(c_);
    }

    ((float4*)out)[row]      = make_float4(hn[0], hn[1], hn[2], hn[3]);  // h_new
    ((float4*)out)[NB + row] = make_float4(cn[0], cn[1], cn[2], cn[3]);  // c_new
}

extern "C" void kernel_launch(void* const* d_in, const int* in_sizes, int n_in,
                              void* d_out, int out_size, void* d_ws, size_t ws_size,
                              hipStream_t stream) {
    const float* x   = (const float*)d_in[0];
    const float* hx  = (const float*)d_in[1];
    const float* cx  = (const float*)d_in[2];
    const float* Wf  = (const float*)d_in[3];
    const float* bf  = (const float*)d_in[4];
    const float* Wi  = (const float*)d_in[5];
    const float* bi  = (const float*)d_in[6];
    const float* Wu  = (const float*)d_in[7];
    const float* bu  = (const float*)d_in[8];
    const float* Wo  = (const float*)d_in[9];
    const float* bo  = (const float*)d_in[10];
    const float* thf = (const float*)d_in[11];
    const float* thi = (const float*)d_in[12];
    const float* thu = (const float*)d_in[13];
    const float* tho = (const float*)d_in[14];

    float* Wp  = (float*)d_ws;            // 260*16 floats = 16640 B
    float* bth = Wp + FANIN * 16;         // 16 floats

    qlstm_prep<<<(FANIN * 16 + TPB - 1) / TPB, TPB, 0, stream>>>(
        Wf, bf, Wi, bi, Wu, bu, Wo, bo, thf, thi, thu, tho, Wp, bth);

    qlstm_main<<<NB / TPB, TPB, 0, stream>>>(
        x, hx, cx, Wp, bth, (float*)d_out);
}